// Round 1
// baseline (92.303 us; speedup 1.0000x reference)
//
#include <hip/hip_runtime.h>

// Problem constants (B,N,M,D fixed by setup_inputs: 4, 4096, 1024, 3)
#define BB 4
#define NN 4096
#define MM 1024
#define NCHUNK 16
#define CHUNK (NN / NCHUNK)   // 256 points1 per chunk in the m->n pass

// ---------------------------------------------------------------------------
// Math note: the reference's einsum 'bnik,bnjk->bnij' over diffs (B,N,10,3)
// builds a 10x10 Gram matrix of rank <= 3, so ev[...,0] (smallest of 10
// ascending eigenvalues) is exactly 0 => curvature == 0 => smoothed == 0.
// Only the chamfer loss (output 0) carries real values.
// ---------------------------------------------------------------------------

__device__ __forceinline__ float block_reduce_sum_256(float v) {
    __shared__ float red[4];
    const int lane = threadIdx.x & 63;
    const int wv   = threadIdx.x >> 6;
    #pragma unroll
    for (int off = 32; off > 0; off >>= 1) v += __shfl_down(v, off, 64);
    if (lane == 0) red[wv] = v;
    __syncthreads();
    float r = 0.0f;
    if (threadIdx.x == 0) r = red[0] + red[1] + red[2] + red[3];
    return r;  // valid in thread 0 only
}

// K0: zero the whole output (loss accumulators + smoothed zeros) and set the
// per-(b,m) running-min workspace to +inf bit pattern.
__global__ void k_init(float* __restrict__ out, unsigned int* __restrict__ wsmin,
                       int out_total) {
    const int i = blockIdx.x * blockDim.x + threadIdx.x;
    if (i < out_total) out[i] = 0.0f;
    if (i < BB * MM) wsmin[i] = 0x7F800000u;  // +inf
}

// K1: loss_term1 = sum_n min_m d2(p1[n], p2[m]).
// One thread per n; points2 batch staged in LDS as (x,y,z,|p|^2).
__global__ __launch_bounds__(256) void chamfer_n2m(const float* __restrict__ p1,
                                                   const float* __restrict__ p2,
                                                   float* __restrict__ out) {
    __shared__ float4 s2[MM];  // 16 KB
    const int b = blockIdx.y;
    const float* p2b = p2 + (size_t)b * MM * 3;
    for (int i = threadIdx.x; i < MM; i += 256) {
        const float x = p2b[3 * i], y = p2b[3 * i + 1], z = p2b[3 * i + 2];
        s2[i] = make_float4(x, y, z, x * x + y * y + z * z);
    }
    __syncthreads();

    const int n = blockIdx.x * 256 + threadIdx.x;
    const float* q = p1 + ((size_t)b * NN + n) * 3;
    const float qx = q[0], qy = q[1], qz = q[2];
    const float qn = qx * qx + qy * qy + qz * qz;

    float mind = 3.402823466e38f;
    #pragma unroll 4
    for (int m = 0; m < MM; ++m) {
        const float4 t = s2[m];  // same addr all lanes -> LDS broadcast
        const float dot = qx * t.x + qy * t.y + qz * t.z;
        const float d2 = qn + t.w - 2.0f * dot;  // reference formula
        mind = fminf(mind, d2);
    }
    mind = fmaxf(mind, 0.0f);  // min(max(d2,0)) == max(min(d2),0)

    const float s = block_reduce_sum_256(mind);
    if (threadIdx.x == 0) atomicAdd(&out[b], s);
}

// K2: partial mins for loss_term2 = sum_m min_n d2. The n-loop is chunked
// across blocks for CU-level parallelism; mins merge via atomicMin on uint
// bit patterns (valid ordering since values are clamped >= 0).
__global__ __launch_bounds__(256) void chamfer_m2n_partial(const float* __restrict__ p1,
                                                           const float* __restrict__ p2,
                                                           unsigned int* __restrict__ wsmin) {
    __shared__ float4 s1[CHUNK];  // 4 KB
    const int b = blockIdx.y;
    const int c = blockIdx.x;
    const float* p1b = p1 + ((size_t)b * NN + (size_t)c * CHUNK) * 3;
    for (int i = threadIdx.x; i < CHUNK; i += 256) {
        const float x = p1b[3 * i], y = p1b[3 * i + 1], z = p1b[3 * i + 2];
        s1[i] = make_float4(x, y, z, x * x + y * y + z * z);
    }
    __syncthreads();

    const float* p2b = p2 + (size_t)b * MM * 3;
    float px[4], py[4], pz[4], pn[4], mv[4];
    #pragma unroll
    for (int j = 0; j < 4; ++j) {
        const int m = threadIdx.x + 256 * j;
        px[j] = p2b[3 * m];
        py[j] = p2b[3 * m + 1];
        pz[j] = p2b[3 * m + 2];
        pn[j] = px[j] * px[j] + py[j] * py[j] + pz[j] * pz[j];
        mv[j] = 3.402823466e38f;
    }
    for (int i = 0; i < CHUNK; ++i) {
        const float4 t = s1[i];
        #pragma unroll
        for (int j = 0; j < 4; ++j) {
            const float dot = px[j] * t.x + py[j] * t.y + pz[j] * t.z;
            const float d2 = pn[j] + t.w - 2.0f * dot;
            mv[j] = fminf(mv[j], d2);
        }
    }
    #pragma unroll
    for (int j = 0; j < 4; ++j) {
        const int m = threadIdx.x + 256 * j;
        const float v = fmaxf(mv[j], 0.0f);
        atomicMin(&wsmin[b * MM + m], __float_as_uint(v));
    }
}

// K3: reduce the per-(b,m) mins and add term2 into out[b].
__global__ __launch_bounds__(256) void chamfer_final(const unsigned int* __restrict__ wsmin,
                                                     float* __restrict__ out) {
    const int b = blockIdx.x;
    float s = 0.0f;
    for (int m = threadIdx.x; m < MM; m += 256)
        s += __uint_as_float(wsmin[b * MM + m]);
    const float t = block_reduce_sum_256(s);
    if (threadIdx.x == 0) atomicAdd(&out[b], t);
}

extern "C" void kernel_launch(void* const* d_in, const int* in_sizes, int n_in,
                              void* d_out, int out_size, void* d_ws, size_t ws_size,
                              hipStream_t stream) {
    const float* p1 = (const float*)d_in[0];  // (B,N,3) fp32
    const float* p2 = (const float*)d_in[1];  // (B,M,3) fp32
    float* out = (float*)d_out;               // [0..3]=total_loss, [4..]=smoothed
    unsigned int* wsmin = (unsigned int*)d_ws;  // B*M uints

    const int total = out_size;  // 4 + B*N = 16388
    const int iblocks = (total + 255) / 256;
    hipLaunchKernelGGL(k_init, dim3(iblocks), dim3(256), 0, stream, out, wsmin, total);
    hipLaunchKernelGGL(chamfer_n2m, dim3(NN / 256, BB), dim3(256), 0, stream, p1, p2, out);
    hipLaunchKernelGGL(chamfer_m2n_partial, dim3(NCHUNK, BB), dim3(256), 0, stream,
                       p1, p2, wsmin);
    hipLaunchKernelGGL(chamfer_final, dim3(BB), dim3(256), 0, stream, wsmin, out);
}

// Round 2
// 24.628 us; speedup vs baseline: 3.7479x; 3.7479x over previous
//
#include <hip/hip_runtime.h>

// Problem constants (B,N,M,D fixed by setup_inputs: 4, 4096, 1024, 3)
#define BB 4
#define NN 4096
#define MM 1024
#define TN 128             // n-tile
#define TM 128             // m-tile
#define CN (NN / TN)       // 32 n-tiles
#define CM (MM / TM)       // 8 m-tiles
#define FLT_BIG 3.402823466e38f

// ---------------------------------------------------------------------------
// Math note: the reference's einsum 'bnik,bnjk->bnij' over diffs (B,N,10,3)
// builds a 10x10 Gram matrix of rank <= 3, so ev[...,0] (smallest of 10
// ascending eigenvalues) is exactly 0 => curvature == 0 => smoothed == 0.
// Only the chamfer loss (output 0) carries real values.
//
// Workspace layout (floats, no atomics — every slot written exactly once):
//   wsN[b][cm][n] : partial min over the cm-th m-tile, for each n   (B*CM*NN)
//   wsM[b][cn][m] : partial min over the cn-th n-tile, for each m   (B*CN*MM)
// Total 262144 floats = 1 MB.
// ---------------------------------------------------------------------------

__device__ __forceinline__ float block_reduce_sum_256(float v) {
    __shared__ float red[4];
    const int lane = threadIdx.x & 63;
    const int wv   = threadIdx.x >> 6;
    #pragma unroll
    for (int off = 32; off > 0; off >>= 1) v += __shfl_down(v, off, 64);
    if (lane == 0) red[wv] = v;
    __syncthreads();
    float r = 0.0f;
    if (threadIdx.x == 0) r = red[0] + red[1] + red[2] + red[3];
    return r;  // valid in thread 0 only
}

// Fused tile kernel: block (cn, cm, b) covers a 128x128 (n,m) tile and
// accumulates BOTH chamfer directions. 1024 blocks -> 4 blocks/CU, 8 waves/CU.
__global__ __launch_bounds__(128) void chamfer_tile(const float* __restrict__ p1,
                                                    const float* __restrict__ p2,
                                                    float* __restrict__ wsN,
                                                    float* __restrict__ wsM) {
    __shared__ float4 sA[TN];  // n-points (x,y,z,|p|^2)
    __shared__ float4 sB[TM];  // m-points
    const int cn = blockIdx.x, cm = blockIdx.y, b = blockIdx.z;
    const int t = threadIdx.x;

    const float* pa = p1 + ((size_t)b * NN + (size_t)cn * TN + t) * 3;
    const float ax = pa[0], ay = pa[1], az = pa[2];
    const float an = ax * ax + ay * ay + az * az;
    sA[t] = make_float4(ax, ay, az, an);

    const float* pb = p2 + ((size_t)b * MM + (size_t)cm * TM + t) * 3;
    const float bx = pb[0], by = pb[1], bz = pb[2];
    const float bn = bx * bx + by * by + bz * bz;
    sB[t] = make_float4(bx, by, bz, bn);
    __syncthreads();

    // Two accumulators per direction to break the fminf dependence chain.
    float mN0 = FLT_BIG, mN1 = FLT_BIG, mM0 = FLT_BIG, mM1 = FLT_BIG;
    #pragma unroll 4
    for (int i = 0; i < TN; i += 2) {
        const float4 u0 = sB[i],     v0 = sA[i];      // broadcast reads
        const float4 u1 = sB[i + 1], v1 = sA[i + 1];
        mN0 = fminf(mN0, an + u0.w - 2.0f * (ax * u0.x + ay * u0.y + az * u0.z));
        mN1 = fminf(mN1, an + u1.w - 2.0f * (ax * u1.x + ay * u1.y + az * u1.z));
        mM0 = fminf(mM0, bn + v0.w - 2.0f * (bx * v0.x + by * v0.y + bz * v0.z));
        mM1 = fminf(mM1, bn + v1.w - 2.0f * (bx * v1.x + by * v1.y + bz * v1.z));
    }
    // clamp: min(max(d2,0)) == max(min(d2),0)
    wsN[((size_t)b * CM + cm) * NN + (size_t)cn * TN + t] = fmaxf(fminf(mN0, mN1), 0.0f);
    wsM[((size_t)b * CN + cn) * MM + (size_t)cm * TM + t] = fmaxf(fminf(mM0, mM1), 0.0f);
}

// Final: min-reduce partials across tiles, sum both terms, write out[b];
// also zero the 'smoothed' outputs.
__global__ __launch_bounds__(256) void chamfer_final(const float* __restrict__ wsN,
                                                     const float* __restrict__ wsM,
                                                     float* __restrict__ out) {
    const int b = blockIdx.x, t = threadIdx.x;

    for (int i = t; i < NN; i += 256) out[4 + b * NN + i] = 0.0f;

    float s = 0.0f;
    for (int n = t; n < NN; n += 256) {  // coalesced: consecutive t -> consecutive n
        float mn = wsN[(size_t)b * CM * NN + n];
        #pragma unroll
        for (int c = 1; c < CM; ++c)
            mn = fminf(mn, wsN[((size_t)b * CM + c) * NN + n]);
        s += mn;
    }
    for (int m = t; m < MM; m += 256) {
        float mn = wsM[(size_t)b * CN * MM + m];
        #pragma unroll
        for (int c = 1; c < CN; ++c)
            mn = fminf(mn, wsM[((size_t)b * CN + c) * MM + m]);
        s += mn;
    }
    const float tot = block_reduce_sum_256(s);
    if (t == 0) out[b] = tot;
}

extern "C" void kernel_launch(void* const* d_in, const int* in_sizes, int n_in,
                              void* d_out, int out_size, void* d_ws, size_t ws_size,
                              hipStream_t stream) {
    const float* p1 = (const float*)d_in[0];  // (B,N,3) fp32
    const float* p2 = (const float*)d_in[1];  // (B,M,3) fp32
    float* out = (float*)d_out;               // [0..3]=total_loss, [4..]=smoothed
    float* wsN = (float*)d_ws;                        // B*CM*NN floats
    float* wsM = wsN + (size_t)BB * CM * NN;          // B*CN*MM floats

    hipLaunchKernelGGL(chamfer_tile, dim3(CN, CM, BB), dim3(TN), 0, stream,
                       p1, p2, wsN, wsM);
    hipLaunchKernelGGL(chamfer_final, dim3(BB), dim3(256), 0, stream, wsN, wsM, out);
}

// Round 3
// 22.300 us; speedup vs baseline: 4.1392x; 1.1044x over previous
//
#include <hip/hip_runtime.h>

// Problem constants (B,N,M,D fixed by setup_inputs: 4, 4096, 1024, 3)
#define BB 4
#define NN 4096
#define MM 1024
#define TN 128             // n-tile
#define TM 128             // m-tile
#define CN (NN / TN)       // 32 n-tiles
#define CM (MM / TM)       // 8 m-tiles
#define FLT_BIG 3.402823466e38f

// ---------------------------------------------------------------------------
// Math note: the reference's einsum 'bnik,bnjk->bnij' over diffs (B,N,10,3)
// builds a 10x10 Gram matrix of rank <= 3, so ev[...,0] (smallest of 10
// ascending eigenvalues) is exactly 0 => curvature == 0 => smoothed == 0.
// Only the chamfer loss (output 0) carries real values.
//
// Workspace layout (ws_size ~256 MB, we use 1.3 MB):
//   pk1 : B*NN float4 (x,y,z,|p|^2) packed points1          (256 KB)
//   pk2 : B*MM float4                                        (64 KB)
//   wsN[b][cm][n] : partial min over m-tile cm, per n        (512 KB)
//   wsM[b][cn][m] : partial min over n-tile cn, per m        (512 KB)
// Every slot written exactly once -> no atomics, no init pass needed.
// ---------------------------------------------------------------------------

__device__ __forceinline__ float block_reduce_sum_256(float v) {
    __shared__ float red[4];
    const int lane = threadIdx.x & 63;
    const int wv   = threadIdx.x >> 6;
    #pragma unroll
    for (int off = 32; off > 0; off >>= 1) v += __shfl_down(v, off, 64);
    if (lane == 0) red[wv] = v;
    __syncthreads();
    float r = 0.0f;
    if (threadIdx.x == 0) r = red[0] + red[1] + red[2] + red[3];
    return r;  // valid in thread 0 only
}

// K0: pack points into aligned float4 (enables s_load_dwordx4 broadcast in the
// tile kernel) and zero all outputs (loss accumulators + smoothed).
__global__ __launch_bounds__(256) void prep(const float* __restrict__ p1,
                                            const float* __restrict__ p2,
                                            float4* __restrict__ pk1,
                                            float4* __restrict__ pk2,
                                            float* __restrict__ out,
                                            int out_total) {
    const int i = blockIdx.x * 256 + threadIdx.x;
    if (i < BB * NN) {
        const float x = p1[3 * i], y = p1[3 * i + 1], z = p1[3 * i + 2];
        pk1[i] = make_float4(x, y, z, x * x + y * y + z * z);
    }
    if (i < BB * MM) {
        const float x = p2[3 * i], y = p2[3 * i + 1], z = p2[3 * i + 2];
        pk2[i] = make_float4(x, y, z, x * x + y * y + z * z);
    }
    if (i < out_total) out[i] = 0.0f;
}

// K1: fused 128x128 (n,m) tile, both chamfer directions. Inner-loop "other
// point" addresses are wave-uniform -> compiler emits s_load_dwordx4 (SGPR
// broadcast, scalar cache); no LDS, no per-lane VMEM in the loop.
__global__ __launch_bounds__(128) void chamfer_tile(const float4* __restrict__ pk1,
                                                    const float4* __restrict__ pk2,
                                                    float* __restrict__ wsN,
                                                    float* __restrict__ wsM) {
    const int cn = blockIdx.x, cm = blockIdx.y, b = blockIdx.z;
    const int t = threadIdx.x;

    const float4 a  = pk1[(size_t)b * NN + (size_t)cn * TN + t];  // own n-point
    const float4 bp = pk2[(size_t)b * MM + (size_t)cm * TM + t];  // own m-point
    const float4* __restrict__ oN = pk2 + (size_t)b * MM + (size_t)cm * TM;  // uniform
    const float4* __restrict__ oM = pk1 + (size_t)b * NN + (size_t)cn * TN;  // uniform

    // Two accumulators per direction to break the fminf dependence chain.
    float mN0 = FLT_BIG, mN1 = FLT_BIG, mM0 = FLT_BIG, mM1 = FLT_BIG;
    #pragma unroll 8
    for (int i = 0; i < TN; i += 2) {
        const float4 u0 = oN[i], u1 = oN[i + 1];
        const float4 v0 = oM[i], v1 = oM[i + 1];
        mN0 = fminf(mN0, (a.w + u0.w) - 2.0f * (a.x * u0.x + a.y * u0.y + a.z * u0.z));
        mN1 = fminf(mN1, (a.w + u1.w) - 2.0f * (a.x * u1.x + a.y * u1.y + a.z * u1.z));
        mM0 = fminf(mM0, (bp.w + v0.w) - 2.0f * (bp.x * v0.x + bp.y * v0.y + bp.z * v0.z));
        mM1 = fminf(mM1, (bp.w + v1.w) - 2.0f * (bp.x * v1.x + bp.y * v1.y + bp.z * v1.z));
    }
    // clamp: min(max(d2,0)) == max(min(d2),0)
    wsN[((size_t)b * CM + cm) * NN + (size_t)cn * TN + t] = fmaxf(fminf(mN0, mN1), 0.0f);
    wsM[((size_t)b * CN + cn) * MM + (size_t)cm * TM + t] = fmaxf(fminf(mM0, mM1), 0.0f);
}

// K2: min-reduce partials across tiles, sum, atomicAdd into out[b].
// Blocks 0..63 handle the B*NN n-slots; blocks 64..79 the B*MM m-slots.
__global__ __launch_bounds__(256) void chamfer_final(const float* __restrict__ wsN,
                                                     const float* __restrict__ wsM,
                                                     float* __restrict__ out) {
    const int t = threadIdx.x;
    float s;
    int b;
    if (blockIdx.x < 64) {
        const int slot = blockIdx.x * 256 + t;  // [0, B*NN); block spans one b
        b = slot / NN;
        const int n = slot % NN;
        float mn = wsN[(size_t)b * CM * NN + n];
        #pragma unroll
        for (int c = 1; c < CM; ++c)
            mn = fminf(mn, wsN[((size_t)b * CM + c) * NN + n]);
        s = mn;
    } else {
        const int slot = (blockIdx.x - 64) * 256 + t;  // [0, B*MM)
        b = slot / MM;
        const int m = slot % MM;
        float mn = wsM[(size_t)b * CN * MM + m];
        #pragma unroll
        for (int c = 1; c < CN; ++c)
            mn = fminf(mn, wsM[((size_t)b * CN + c) * MM + m]);
        s = mn;
    }
    const float tot = block_reduce_sum_256(s);
    if (t == 0) atomicAdd(&out[b], tot);
}

extern "C" void kernel_launch(void* const* d_in, const int* in_sizes, int n_in,
                              void* d_out, int out_size, void* d_ws, size_t ws_size,
                              hipStream_t stream) {
    const float* p1 = (const float*)d_in[0];  // (B,N,3) fp32
    const float* p2 = (const float*)d_in[1];  // (B,M,3) fp32
    float* out = (float*)d_out;               // [0..3]=total_loss, [4..]=smoothed

    float4* pk1 = (float4*)d_ws;                       // B*NN float4
    float4* pk2 = pk1 + (size_t)BB * NN;               // B*MM float4
    float* wsN = (float*)(pk2 + (size_t)BB * MM);      // B*CM*NN floats
    float* wsM = wsN + (size_t)BB * CM * NN;           // B*CN*MM floats

    const int total = out_size;  // 4 + B*N = 16388
    hipLaunchKernelGGL(prep, dim3((total + 255) / 256), dim3(256), 0, stream,
                       p1, p2, pk1, pk2, out, total);
    hipLaunchKernelGGL(chamfer_tile, dim3(CN, CM, BB), dim3(TN), 0, stream,
                       pk1, pk2, wsN, wsM);
    hipLaunchKernelGGL(chamfer_final, dim3(64 + 16), dim3(256), 0, stream,
                       wsN, wsM, out);
}